// Round 3
// baseline (677.682 us; speedup 1.0000x reference)
//
#include <hip/hip_runtime.h>
#include <math.h>

#define N_NODES 50000
#define N_EDGES 800000
#define F_IN 128
#define HIDDEN 256
#define N_CLASSES 40

// ---------------- bf16 helpers ----------------

__device__ __forceinline__ float bf2f(unsigned short u) {
    unsigned int t = ((unsigned int)u) << 16;
    float f;
    __builtin_memcpy(&f, &t, 4);
    return f;
}

__device__ __forceinline__ unsigned short f2bf(float f) {
    unsigned int t;
    __builtin_memcpy(&t, &f, 4);
    unsigned int r = (t + 0x7fffu + ((t >> 16) & 1u)) >> 16;  // RNE
    return (unsigned short)r;
}

// ---------------- CSR build ----------------

__global__ void zero_counts(int* __restrict__ counts) {
    int i = blockIdx.x * blockDim.x + threadIdx.x;
    if (i < N_NODES) counts[i] = 0;
}

// edge_index arrives as int32 (JAX default x64-disabled downgrades int64).
__global__ void count_kernel(const int* __restrict__ dst, int* __restrict__ counts) {
    int e = blockIdx.x * blockDim.x + threadIdx.x;
    if (e < N_EDGES) {
        int d = dst[e];
        d = (d < 0) ? 0 : (d >= N_NODES ? N_NODES - 1 : d);  // defensive clamp
        atomicAdd(&counts[d], 1);
    }
}

__global__ __launch_bounds__(1024) void scan_kernel(const int* __restrict__ counts,
                                                    int* __restrict__ row_off,
                                                    int* __restrict__ cursor,
                                                    float* __restrict__ inv_deg) {
    __shared__ int sdata[1024];
    __shared__ int s_carry;
    int tid = threadIdx.x;
    if (tid == 0) s_carry = 0;
    __syncthreads();
    for (int base = 0; base < N_NODES; base += 1024) {
        int i = base + tid;
        int v = (i < N_NODES) ? counts[i] : 0;
        sdata[tid] = v;
        __syncthreads();
        for (int off = 1; off < 1024; off <<= 1) {
            int t = (tid >= off) ? sdata[tid - off] : 0;
            __syncthreads();
            sdata[tid] += t;
            __syncthreads();
        }
        int incl = sdata[tid];
        int carry = s_carry;
        if (i < N_NODES) {
            int excl = carry + incl - v;
            row_off[i] = excl;
            cursor[i] = excl;
            inv_deg[i] = 1.0f / fmaxf((float)v, 1.0f);
        }
        __syncthreads();
        if (tid == 1023) s_carry = carry + incl;
        __syncthreads();
    }
    if (tid == 0) row_off[N_NODES] = s_carry;
}

__global__ void fill_kernel(const int* __restrict__ ei, int* __restrict__ cursor,
                            int* __restrict__ csr_src) {
    int e = blockIdx.x * blockDim.x + threadIdx.x;
    if (e < N_EDGES) {
        int s = ei[e];
        int d = ei[N_EDGES + e];
        s = (s < 0) ? 0 : (s >= N_NODES ? N_NODES - 1 : s);
        d = (d < 0) ? 0 : (d >= N_NODES ? N_NODES - 1 : d);
        int pos = atomicAdd(&cursor[d], 1);
        if (pos >= 0 && pos < N_EDGES) csr_src[pos] = s;
    }
}

// ---------------- layer 1: fused gather-mean + GEMM + relu -> h (bf16) ----------------
// 256 threads (4 waves), 16 nodes/block. Phase 1: wave-per-node gather into LDS.
// Phase 2: thread = output column c (0..255), 16-row register tile.

__global__ __launch_bounds__(256) void gemm1_fused(
    const float* __restrict__ x, const int* __restrict__ row_off,
    const int* __restrict__ csr_src, const float* __restrict__ inv_deg,
    const float* __restrict__ W1l, const float* __restrict__ W1r,
    const float* __restrict__ b1, unsigned short* __restrict__ h16) {
    __shared__ float As[16][2 * F_IN];
    int n0 = blockIdx.x * 16;
    int tid = threadIdx.x;
    int wave = tid >> 6;
    int lane = tid & 63;

    for (int j = wave; j < 16; j += 4) {
        int n = n0 + j;
        int e0 = row_off[n], e1 = row_off[n + 1];
        float ax = 0.f, ay = 0.f;
        int e = e0;
        for (; e + 1 < e1; e += 2) {
            int s0 = csr_src[e], s1 = csr_src[e + 1];
            float2 v0 = *reinterpret_cast<const float2*>(x + (size_t)s0 * F_IN + lane * 2);
            float2 v1 = *reinterpret_cast<const float2*>(x + (size_t)s1 * F_IN + lane * 2);
            ax += v0.x + v1.x;
            ay += v0.y + v1.y;
        }
        if (e < e1) {
            int s0 = csr_src[e];
            float2 v0 = *reinterpret_cast<const float2*>(x + (size_t)s0 * F_IN + lane * 2);
            ax += v0.x;
            ay += v0.y;
        }
        float id = inv_deg[n];
        As[j][lane * 2] = ax * id;
        As[j][lane * 2 + 1] = ay * id;
        float2 xv = *reinterpret_cast<const float2*>(x + (size_t)n * F_IN + lane * 2);
        As[j][F_IN + lane * 2] = xv.x;
        As[j][F_IN + lane * 2 + 1] = xv.y;
    }
    __syncthreads();

    int c = tid;
    float acc[16];
#pragma unroll
    for (int i = 0; i < 16; ++i) acc[i] = 0.f;
    for (int k4 = 0; k4 < F_IN; k4 += 4) {
        float w0 = W1l[(k4 + 0) * HIDDEN + c];
        float w1 = W1l[(k4 + 1) * HIDDEN + c];
        float w2 = W1l[(k4 + 2) * HIDDEN + c];
        float w3 = W1l[(k4 + 3) * HIDDEN + c];
#pragma unroll
        for (int i = 0; i < 16; ++i) {
            float4 a = *reinterpret_cast<const float4*>(&As[i][k4]);
            acc[i] += a.x * w0 + a.y * w1 + a.z * w2 + a.w * w3;
        }
    }
    for (int k4 = 0; k4 < F_IN; k4 += 4) {
        float w0 = W1r[(k4 + 0) * HIDDEN + c];
        float w1 = W1r[(k4 + 1) * HIDDEN + c];
        float w2 = W1r[(k4 + 2) * HIDDEN + c];
        float w3 = W1r[(k4 + 3) * HIDDEN + c];
#pragma unroll
        for (int i = 0; i < 16; ++i) {
            float4 a = *reinterpret_cast<const float4*>(&As[i][F_IN + k4]);
            acc[i] += a.x * w0 + a.y * w1 + a.z * w2 + a.w * w3;
        }
    }
    float bb = b1[c];
#pragma unroll
    for (int i = 0; i < 16; ++i)
        h16[(size_t)(n0 + i) * HIDDEN + c] = f2bf(fmaxf(acc[i] + bb, 0.f));
}

// ---------------- layer 2: fused gather-mean + GEMM + log_softmax ----------------
// 320 threads (5 waves), 24 nodes/block. Phase 1: wave-per-node gather (bf16 h).
// Phase 2: thread = (col c 0..39, group g 0..7), 3-row tile. Then LSM epilogue.

#define NB2 24
#define AS2_STRIDE (2 * HIDDEN + 4)  // 516 floats: float4-aligned rows, non-pow2 stride

__global__ __launch_bounds__(320) void gemm2_fused(
    const unsigned short* __restrict__ h16, const int* __restrict__ row_off,
    const int* __restrict__ csr_src, const float* __restrict__ inv_deg,
    const float* __restrict__ W2l, const float* __restrict__ W2r,
    const float* __restrict__ b2, float* __restrict__ out) {
    __shared__ float As[NB2][AS2_STRIDE];
    __shared__ float lse[NB2];
    int n0 = blockIdx.x * NB2;
    int tid = threadIdx.x;
    int wave = tid >> 6;
    int lane = tid & 63;

    for (int j = wave; j < NB2; j += 5) {
        int n = n0 + j;
        if (n < N_NODES) {
            int e0 = row_off[n], e1 = row_off[n + 1];
            float ax = 0.f, ay = 0.f, az = 0.f, aw = 0.f;
            int e = e0;
            for (; e + 1 < e1; e += 2) {
                int s0 = csr_src[e], s1 = csr_src[e + 1];
                ushort4 v0 = *reinterpret_cast<const ushort4*>(h16 + (size_t)s0 * HIDDEN + lane * 4);
                ushort4 v1 = *reinterpret_cast<const ushort4*>(h16 + (size_t)s1 * HIDDEN + lane * 4);
                ax += bf2f(v0.x) + bf2f(v1.x);
                ay += bf2f(v0.y) + bf2f(v1.y);
                az += bf2f(v0.z) + bf2f(v1.z);
                aw += bf2f(v0.w) + bf2f(v1.w);
            }
            if (e < e1) {
                int s0 = csr_src[e];
                ushort4 v0 = *reinterpret_cast<const ushort4*>(h16 + (size_t)s0 * HIDDEN + lane * 4);
                ax += bf2f(v0.x);
                ay += bf2f(v0.y);
                az += bf2f(v0.z);
                aw += bf2f(v0.w);
            }
            float id = inv_deg[n];
            float4 m;
            m.x = ax * id; m.y = ay * id; m.z = az * id; m.w = aw * id;
            *reinterpret_cast<float4*>(&As[j][lane * 4]) = m;
            ushort4 sv = *reinterpret_cast<const ushort4*>(h16 + (size_t)n * HIDDEN + lane * 4);
            float4 s;
            s.x = bf2f(sv.x); s.y = bf2f(sv.y); s.z = bf2f(sv.z); s.w = bf2f(sv.w);
            *reinterpret_cast<float4*>(&As[j][HIDDEN + lane * 4]) = s;
        } else {
            float4 z = {0.f, 0.f, 0.f, 0.f};
            *reinterpret_cast<float4*>(&As[j][lane * 4]) = z;
            *reinterpret_cast<float4*>(&As[j][HIDDEN + lane * 4]) = z;
        }
    }
    __syncthreads();

    int c = tid % 40;
    int g = tid / 40;  // 0..7
    float acc[3] = {0.f, 0.f, 0.f};
    for (int k4 = 0; k4 < HIDDEN; k4 += 4) {
        float w0 = W2l[(k4 + 0) * N_CLASSES + c];
        float w1 = W2l[(k4 + 1) * N_CLASSES + c];
        float w2 = W2l[(k4 + 2) * N_CLASSES + c];
        float w3 = W2l[(k4 + 3) * N_CLASSES + c];
#pragma unroll
        for (int i = 0; i < 3; ++i) {
            float4 a = *reinterpret_cast<const float4*>(&As[g + 8 * i][k4]);
            acc[i] += a.x * w0 + a.y * w1 + a.z * w2 + a.w * w3;
        }
    }
    for (int k4 = 0; k4 < HIDDEN; k4 += 4) {
        float w0 = W2r[(k4 + 0) * N_CLASSES + c];
        float w1 = W2r[(k4 + 1) * N_CLASSES + c];
        float w2 = W2r[(k4 + 2) * N_CLASSES + c];
        float w3 = W2r[(k4 + 3) * N_CLASSES + c];
#pragma unroll
        for (int i = 0; i < 3; ++i) {
            float4 a = *reinterpret_cast<const float4*>(&As[g + 8 * i][HIDDEN + k4]);
            acc[i] += a.x * w0 + a.y * w1 + a.z * w2 + a.w * w3;
        }
    }
    float bb = b2[c];
    __syncthreads();
    float* out_s = &As[0][0];  // reuse LDS as 24x40 output tile
#pragma unroll
    for (int i = 0; i < 3; ++i) out_s[(g + 8 * i) * N_CLASSES + c] = acc[i] + bb;
    __syncthreads();
    if (tid < NB2) {
        float m = -1e30f;
        for (int j = 0; j < N_CLASSES; ++j) m = fmaxf(m, out_s[tid * N_CLASSES + j]);
        float s = 0.f;
        for (int j = 0; j < N_CLASSES; ++j) s += expf(out_s[tid * N_CLASSES + j] - m);
        lse[tid] = m + logf(s);
    }
    __syncthreads();
    for (int idx = tid; idx < NB2 * N_CLASSES; idx += 320) {
        int i = idx / N_CLASSES;
        int n = n0 + i;
        if (n < N_NODES) out[(size_t)n * N_CLASSES + (idx % N_CLASSES)] = out_s[idx] - lse[i];
    }
}

// ---------------- launch ----------------

extern "C" void kernel_launch(void* const* d_in, const int* in_sizes, int n_in,
                              void* d_out, int out_size, void* d_ws, size_t ws_size,
                              hipStream_t stream) {
    const float* x = (const float*)d_in[0];
    const int* ei = (const int*)d_in[1];  // int32 per harness contract
    const float* W1l = (const float*)d_in[2];
    const float* W1r = (const float*)d_in[3];
    const float* b1 = (const float*)d_in[4];
    const float* W2l = (const float*)d_in[5];
    const float* W2r = (const float*)d_in[6];
    const float* b2 = (const float*)d_in[7];
    float* out = (float*)d_out;

    char* p = (char*)d_ws;
    size_t off = 0;
    auto take = [&](size_t bytes) -> void* {
        void* r = p + off;
        off = (off + bytes + 255) & ~(size_t)255;
        return r;
    };
    int* counts = (int*)take(N_NODES * sizeof(int));
    int* row_off = (int*)take((N_NODES + 1) * sizeof(int));
    int* cursor = (int*)take(N_NODES * sizeof(int));
    float* invdeg = (float*)take(N_NODES * sizeof(float));
    int* csr_src = (int*)take(N_EDGES * sizeof(int));
    unsigned short* h16 = (unsigned short*)take((size_t)N_NODES * HIDDEN * sizeof(unsigned short));
    // total ~= 30 MB

    zero_counts<<<(N_NODES + 255) / 256, 256, 0, stream>>>(counts);
    count_kernel<<<(N_EDGES + 255) / 256, 256, 0, stream>>>(ei + N_EDGES, counts);
    scan_kernel<<<1, 1024, 0, stream>>>(counts, row_off, cursor, invdeg);
    fill_kernel<<<(N_EDGES + 255) / 256, 256, 0, stream>>>(ei, cursor, csr_src);
    gemm1_fused<<<N_NODES / 16, 256, 0, stream>>>(x, row_off, csr_src, invdeg, W1l, W1r, b1, h16);
    gemm2_fused<<<(N_NODES + NB2 - 1) / NB2, 320, 0, stream>>>(h16, row_off, csr_src, invdeg,
                                                               W2l, W2r, b2, out);
}

// Round 4
// 437.429 us; speedup vs baseline: 1.5492x; 1.5492x over previous
//
#include <hip/hip_runtime.h>
#include <math.h>

#define N_NODES 50000
#define N_EDGES 800000
#define F_IN 128
#define HIDDEN 256
#define N_CLASSES 40

typedef __attribute__((ext_vector_type(8))) short bf16x8;
typedef __attribute__((ext_vector_type(4))) float f32x4;

// ---------------- bf16 helpers ----------------

__device__ __forceinline__ float bf2f(unsigned short u) {
    unsigned int t = ((unsigned int)u) << 16;
    float f;
    __builtin_memcpy(&f, &t, 4);
    return f;
}

__device__ __forceinline__ unsigned short f2bf(float f) {
    unsigned int t;
    __builtin_memcpy(&t, &f, 4);
    unsigned int r = (t + 0x7fffu + ((t >> 16) & 1u)) >> 16;  // RNE
    return (unsigned short)r;
}

// ---------------- CSR build ----------------

__global__ void zero_counts(int* __restrict__ counts) {
    int i = blockIdx.x * blockDim.x + threadIdx.x;
    if (i < N_NODES) counts[i] = 0;
}

// edge_index arrives as int32 (JAX x64-disabled downgrades int64)
__global__ void count_kernel(const int* __restrict__ dst, int* __restrict__ counts) {
    int e = blockIdx.x * blockDim.x + threadIdx.x;
    if (e < N_EDGES) {
        int d = dst[e];
        d = (d < 0) ? 0 : (d >= N_NODES ? N_NODES - 1 : d);
        atomicAdd(&counts[d], 1);
    }
}

__global__ __launch_bounds__(1024) void scan_kernel(const int* __restrict__ counts,
                                                    int* __restrict__ row_off,
                                                    int* __restrict__ cursor,
                                                    float* __restrict__ inv_deg) {
    __shared__ int sdata[1024];
    __shared__ int s_carry;
    int tid = threadIdx.x;
    if (tid == 0) s_carry = 0;
    __syncthreads();
    for (int base = 0; base < N_NODES; base += 1024) {
        int i = base + tid;
        int v = (i < N_NODES) ? counts[i] : 0;
        sdata[tid] = v;
        __syncthreads();
        for (int off = 1; off < 1024; off <<= 1) {
            int t = (tid >= off) ? sdata[tid - off] : 0;
            __syncthreads();
            sdata[tid] += t;
            __syncthreads();
        }
        int incl = sdata[tid];
        int carry = s_carry;
        if (i < N_NODES) {
            int excl = carry + incl - v;
            row_off[i] = excl;
            cursor[i] = excl;
            inv_deg[i] = 1.0f / fmaxf((float)v, 1.0f);
        }
        __syncthreads();
        if (tid == 1023) s_carry = carry + incl;
        __syncthreads();
    }
    if (tid == 0) row_off[N_NODES] = s_carry;
}

__global__ void fill_kernel(const int* __restrict__ ei, int* __restrict__ cursor,
                            int* __restrict__ csr_src) {
    int e = blockIdx.x * blockDim.x + threadIdx.x;
    if (e < N_EDGES) {
        int s = ei[e];
        int d = ei[N_EDGES + e];
        s = (s < 0) ? 0 : (s >= N_NODES ? N_NODES - 1 : s);
        d = (d < 0) ? 0 : (d >= N_NODES ? N_NODES - 1 : d);
        int pos = atomicAdd(&cursor[d], 1);
        if (pos >= 0 && pos < N_EDGES) csr_src[pos] = s;
    }
}

// ---------------- W1 pack: Wpk[n][k] bf16, k<128 -> W1l[k][n], else W1r ----------------

__global__ void pack_w1(const float* __restrict__ W1l, const float* __restrict__ W1r,
                        unsigned short* __restrict__ Wpk) {
    int n = blockIdx.x;   // 0..255
    int k = threadIdx.x;  // 0..255
    float v = (k < F_IN) ? W1l[(size_t)k * HIDDEN + n] : W1r[(size_t)(k - F_IN) * HIDDEN + n];
    Wpk[(size_t)n * 256 + k] = f2bf(v);
}

// ---------------- layer 1: gather-mean + MFMA GEMM + relu -> h (bf16) ----------------
// 256 threads (4 waves), 16 nodes/block. LDS A-tile [16][256] bf16 (stride 264).
// MFMA 16x16x32 bf16: per wave 4 n-tiles, 8 k-steps.

#define AS1_STRIDE 264  // bf16 units; 528 B row, 16B-multiple

__global__ __launch_bounds__(256) void gemm1_fused(
    const float* __restrict__ x, const int* __restrict__ row_off,
    const int* __restrict__ csr_src, const float* __restrict__ inv_deg,
    const unsigned short* __restrict__ Wpk, const float* __restrict__ b1,
    unsigned short* __restrict__ h16) {
    __shared__ __align__(16) unsigned short As[16][AS1_STRIDE];
    int n0 = blockIdx.x * 16;
    int tid = threadIdx.x;
    int wave = tid >> 6;
    int lane = tid & 63;

    // ---- gather phase: wave-per-node, 4 nodes/wave, edge loop unrolled x4 ----
    for (int j = wave; j < 16; j += 4) {
        int n = n0 + j;
        int e0 = row_off[n], e1 = row_off[n + 1];
        float ax = 0.f, ay = 0.f;
        int e = e0;
        for (; e + 3 < e1; e += 4) {
            int s0 = csr_src[e], s1 = csr_src[e + 1];
            int s2 = csr_src[e + 2], s3 = csr_src[e + 3];
            float2 v0 = *reinterpret_cast<const float2*>(x + (size_t)s0 * F_IN + lane * 2);
            float2 v1 = *reinterpret_cast<const float2*>(x + (size_t)s1 * F_IN + lane * 2);
            float2 v2 = *reinterpret_cast<const float2*>(x + (size_t)s2 * F_IN + lane * 2);
            float2 v3 = *reinterpret_cast<const float2*>(x + (size_t)s3 * F_IN + lane * 2);
            ax += (v0.x + v1.x) + (v2.x + v3.x);
            ay += (v0.y + v1.y) + (v2.y + v3.y);
        }
        for (; e < e1; ++e) {
            int s0 = csr_src[e];
            float2 v0 = *reinterpret_cast<const float2*>(x + (size_t)s0 * F_IN + lane * 2);
            ax += v0.x;
            ay += v0.y;
        }
        float id = inv_deg[n];
        unsigned int pm = (unsigned int)f2bf(ax * id) | ((unsigned int)f2bf(ay * id) << 16);
        *reinterpret_cast<unsigned int*>(&As[j][lane * 2]) = pm;
        float2 xv = *reinterpret_cast<const float2*>(x + (size_t)n * F_IN + lane * 2);
        unsigned int px = (unsigned int)f2bf(xv.x) | ((unsigned int)f2bf(xv.y) << 16);
        *reinterpret_cast<unsigned int*>(&As[j][F_IN + lane * 2]) = px;
    }
    __syncthreads();

    // ---- MFMA phase: wave handles n-tiles wave*4 .. wave*4+3 ----
    int mrow = lane & 15;   // A row / D col selector
    int kg = lane >> 4;     // 0..3
    f32x4 acc0 = {0.f, 0.f, 0.f, 0.f};
    f32x4 acc1 = {0.f, 0.f, 0.f, 0.f};
    f32x4 acc2 = {0.f, 0.f, 0.f, 0.f};
    f32x4 acc3 = {0.f, 0.f, 0.f, 0.f};
    const unsigned short* wp = Wpk + ((size_t)(wave * 4) * 16 + mrow) * 256 + kg * 8;
#pragma unroll
    for (int ks = 0; ks < 8; ++ks) {
        bf16x8 a = *reinterpret_cast<const bf16x8*>(&As[mrow][ks * 32 + kg * 8]);
        bf16x8 b0 = *reinterpret_cast<const bf16x8*>(wp + 0 * 16 * 256 + ks * 32);
        bf16x8 b1f = *reinterpret_cast<const bf16x8*>(wp + 1 * 16 * 256 + ks * 32);
        bf16x8 b2 = *reinterpret_cast<const bf16x8*>(wp + 2 * 16 * 256 + ks * 32);
        bf16x8 b3 = *reinterpret_cast<const bf16x8*>(wp + 3 * 16 * 256 + ks * 32);
        acc0 = __builtin_amdgcn_mfma_f32_16x16x32_bf16(a, b0, acc0, 0, 0, 0);
        acc1 = __builtin_amdgcn_mfma_f32_16x16x32_bf16(a, b1f, acc1, 0, 0, 0);
        acc2 = __builtin_amdgcn_mfma_f32_16x16x32_bf16(a, b2, acc2, 0, 0, 0);
        acc3 = __builtin_amdgcn_mfma_f32_16x16x32_bf16(a, b3, acc3, 0, 0, 0);
    }
    // D layout: col = lane&15 (n), row = (lane>>4)*4 + r (node)
    f32x4 accs[4] = {acc0, acc1, acc2, acc3};
#pragma unroll
    for (int i = 0; i < 4; ++i) {
        int n = (wave * 4 + i) * 16 + mrow;
        float bb = b1[n];
#pragma unroll
        for (int r = 0; r < 4; ++r) {
            int row = kg * 4 + r;
            h16[(size_t)(n0 + row) * HIDDEN + n] = f2bf(fmaxf(accs[i][r] + bb, 0.f));
        }
    }
}

// ---------------- layer 2: gather-mean + f32 GEMM + log_softmax ----------------
// 320 threads (5 waves), 24 nodes/block. LDS A-tile [24][512] bf16 (stride 520).

#define NB2 24
#define AS2_STRIDE 520  // bf16 units; 1040 B row

__global__ __launch_bounds__(320) void gemm2_fused(
    const unsigned short* __restrict__ h16, const int* __restrict__ row_off,
    const int* __restrict__ csr_src, const float* __restrict__ inv_deg,
    const float* __restrict__ W2l, const float* __restrict__ W2r,
    const float* __restrict__ b2, float* __restrict__ out) {
    __shared__ __align__(16) unsigned short As[NB2][AS2_STRIDE];
    __shared__ float lse[NB2];
    int n0 = blockIdx.x * NB2;
    int tid = threadIdx.x;
    int wave = tid >> 6;
    int lane = tid & 63;

    // ---- gather phase: wave-per-node, edge loop unrolled x4 ----
    for (int j = wave; j < NB2; j += 5) {
        int n = n0 + j;
        if (n < N_NODES) {
            int e0 = row_off[n], e1 = row_off[n + 1];
            float ax = 0.f, ay = 0.f, az = 0.f, aw = 0.f;
            int e = e0;
            for (; e + 3 < e1; e += 4) {
                int s0 = csr_src[e], s1 = csr_src[e + 1];
                int s2 = csr_src[e + 2], s3 = csr_src[e + 3];
                ushort4 v0 = *reinterpret_cast<const ushort4*>(h16 + (size_t)s0 * HIDDEN + lane * 4);
                ushort4 v1 = *reinterpret_cast<const ushort4*>(h16 + (size_t)s1 * HIDDEN + lane * 4);
                ushort4 v2 = *reinterpret_cast<const ushort4*>(h16 + (size_t)s2 * HIDDEN + lane * 4);
                ushort4 v3 = *reinterpret_cast<const ushort4*>(h16 + (size_t)s3 * HIDDEN + lane * 4);
                ax += (bf2f(v0.x) + bf2f(v1.x)) + (bf2f(v2.x) + bf2f(v3.x));
                ay += (bf2f(v0.y) + bf2f(v1.y)) + (bf2f(v2.y) + bf2f(v3.y));
                az += (bf2f(v0.z) + bf2f(v1.z)) + (bf2f(v2.z) + bf2f(v3.z));
                aw += (bf2f(v0.w) + bf2f(v1.w)) + (bf2f(v2.w) + bf2f(v3.w));
            }
            for (; e < e1; ++e) {
                int s0 = csr_src[e];
                ushort4 v0 = *reinterpret_cast<const ushort4*>(h16 + (size_t)s0 * HIDDEN + lane * 4);
                ax += bf2f(v0.x);
                ay += bf2f(v0.y);
                az += bf2f(v0.z);
                aw += bf2f(v0.w);
            }
            float id = inv_deg[n];
            ushort4 m;
            m.x = f2bf(ax * id); m.y = f2bf(ay * id); m.z = f2bf(az * id); m.w = f2bf(aw * id);
            *reinterpret_cast<ushort4*>(&As[j][lane * 4]) = m;
            // self row: already bf16, plain copy
            *reinterpret_cast<ushort4*>(&As[j][HIDDEN + lane * 4]) =
                *reinterpret_cast<const ushort4*>(h16 + (size_t)n * HIDDEN + lane * 4);
        } else {
            ushort4 z = {0, 0, 0, 0};
            *reinterpret_cast<ushort4*>(&As[j][lane * 4]) = z;
            *reinterpret_cast<ushort4*>(&As[j][HIDDEN + lane * 4]) = z;
        }
    }
    __syncthreads();

    // ---- GEMM phase: thread = (col c 0..39, group g 0..7), rows {g, g+8, g+16} ----
    int c = tid % 40;
    int g = tid / 40;
    float acc[3] = {0.f, 0.f, 0.f};
    for (int k = 0; k < HIDDEN; k += 4) {
        float w0 = W2l[(k + 0) * N_CLASSES + c];
        float w1 = W2l[(k + 1) * N_CLASSES + c];
        float w2 = W2l[(k + 2) * N_CLASSES + c];
        float w3 = W2l[(k + 3) * N_CLASSES + c];
#pragma unroll
        for (int i = 0; i < 3; ++i) {
            ushort4 a = *reinterpret_cast<const ushort4*>(&As[g + 8 * i][k]);
            acc[i] += bf2f(a.x) * w0 + bf2f(a.y) * w1 + bf2f(a.z) * w2 + bf2f(a.w) * w3;
        }
    }
    for (int k = 0; k < HIDDEN; k += 4) {
        float w0 = W2r[(k + 0) * N_CLASSES + c];
        float w1 = W2r[(k + 1) * N_CLASSES + c];
        float w2 = W2r[(k + 2) * N_CLASSES + c];
        float w3 = W2r[(k + 3) * N_CLASSES + c];
#pragma unroll
        for (int i = 0; i < 3; ++i) {
            ushort4 a = *reinterpret_cast<const ushort4*>(&As[g + 8 * i][HIDDEN + k]);
            acc[i] += bf2f(a.x) * w0 + bf2f(a.y) * w1 + bf2f(a.z) * w2 + bf2f(a.w) * w3;
        }
    }
    float bb = b2[c];
    __syncthreads();
    float* out_s = reinterpret_cast<float*>(&As[0][0]);  // reuse LDS as 24x40 f32 tile
#pragma unroll
    for (int i = 0; i < 3; ++i) out_s[(g + 8 * i) * N_CLASSES + c] = acc[i] + bb;
    __syncthreads();
    if (tid < NB2) {
        float m = -1e30f;
        for (int j = 0; j < N_CLASSES; ++j) m = fmaxf(m, out_s[tid * N_CLASSES + j]);
        float s = 0.f;
        for (int j = 0; j < N_CLASSES; ++j) s += expf(out_s[tid * N_CLASSES + j] - m);
        lse[tid] = m + logf(s);
    }
    __syncthreads();
    for (int idx = tid; idx < NB2 * N_CLASSES; idx += 320) {
        int i = idx / N_CLASSES;
        int n = n0 + i;
        if (n < N_NODES) out[(size_t)n * N_CLASSES + (idx % N_CLASSES)] = out_s[idx] - lse[i];
    }
}

// ---------------- launch ----------------

extern "C" void kernel_launch(void* const* d_in, const int* in_sizes, int n_in,
                              void* d_out, int out_size, void* d_ws, size_t ws_size,
                              hipStream_t stream) {
    const float* x = (const float*)d_in[0];
    const int* ei = (const int*)d_in[1];  // int32 per harness contract
    const float* W1l = (const float*)d_in[2];
    const float* W1r = (const float*)d_in[3];
    const float* b1 = (const float*)d_in[4];
    const float* W2l = (const float*)d_in[5];
    const float* W2r = (const float*)d_in[6];
    const float* b2 = (const float*)d_in[7];
    float* out = (float*)d_out;

    char* p = (char*)d_ws;
    size_t off = 0;
    auto take = [&](size_t bytes) -> void* {
        void* r = p + off;
        off = (off + bytes + 255) & ~(size_t)255;
        return r;
    };
    int* counts = (int*)take(N_NODES * sizeof(int));
    int* row_off = (int*)take((N_NODES + 1) * sizeof(int));
    int* cursor = (int*)take(N_NODES * sizeof(int));
    float* invdeg = (float*)take(N_NODES * sizeof(float));
    int* csr_src = (int*)take(N_EDGES * sizeof(int));
    unsigned short* h16 = (unsigned short*)take((size_t)N_NODES * HIDDEN * sizeof(unsigned short));
    unsigned short* Wpk = (unsigned short*)take(256 * 256 * sizeof(unsigned short));
    // total ~= 30 MB

    zero_counts<<<(N_NODES + 255) / 256, 256, 0, stream>>>(counts);
    count_kernel<<<(N_EDGES + 255) / 256, 256, 0, stream>>>(ei + N_EDGES, counts);
    scan_kernel<<<1, 1024, 0, stream>>>(counts, row_off, cursor, invdeg);
    fill_kernel<<<(N_EDGES + 255) / 256, 256, 0, stream>>>(ei, cursor, csr_src);
    pack_w1<<<256, 256, 0, stream>>>(W1l, W1r, Wpk);
    gemm1_fused<<<N_NODES / 16, 256, 0, stream>>>(x, row_off, csr_src, invdeg, Wpk, b1, h16);
    gemm2_fused<<<(N_NODES + NB2 - 1) / NB2, 320, 0, stream>>>(h16, row_off, csr_src, invdeg,
                                                               W2l, W2r, b2, out);
}

// Round 5
// 434.025 us; speedup vs baseline: 1.5614x; 1.0078x over previous
//
#include <hip/hip_runtime.h>
#include <math.h>

#define N_NODES 50000
#define N_EDGES 800000
#define F_IN 128
#define HIDDEN 256
#define N_CLASSES 40

typedef __attribute__((ext_vector_type(8))) short bf16x8;
typedef __attribute__((ext_vector_type(4))) float f32x4;

// ---------------- bf16 helpers ----------------

__device__ __forceinline__ float bf2f(unsigned short u) {
    unsigned int t = ((unsigned int)u) << 16;
    float f;
    __builtin_memcpy(&f, &t, 4);
    return f;
}

__device__ __forceinline__ unsigned short f2bf(float f) {
    unsigned int t;
    __builtin_memcpy(&t, &f, 4);
    unsigned int r = (t + 0x7fffu + ((t >> 16) & 1u)) >> 16;  // RNE
    return (unsigned short)r;
}

// ---------------- CSR build ----------------

__global__ void zero_counts(int* __restrict__ counts) {
    int i = blockIdx.x * blockDim.x + threadIdx.x;
    if (i < N_NODES) counts[i] = 0;
}

// edge_index arrives as int32 (JAX x64-disabled downgrades int64)
__global__ void count_kernel(const int* __restrict__ dst, int* __restrict__ counts) {
    int e = blockIdx.x * blockDim.x + threadIdx.x;
    if (e < N_EDGES) {
        int d = dst[e];
        d = (d < 0) ? 0 : (d >= N_NODES ? N_NODES - 1 : d);
        atomicAdd(&counts[d], 1);
    }
}

// single-block scan: 1024 threads x 49-element serial segments, one LDS scan of partials
#define SEG 49
__global__ __launch_bounds__(1024) void scan_kernel(const int* __restrict__ counts,
                                                    int* __restrict__ row_off,
                                                    int* __restrict__ cursor,
                                                    float* __restrict__ inv_deg) {
    __shared__ int part[1024];
    int tid = threadIdx.x;
    int beg = tid * SEG;
    int end = beg + SEG;
    if (end > N_NODES) end = N_NODES;
    int sum = 0;
    for (int i = beg; i < end; ++i) sum += counts[i];
    part[tid] = sum;
    __syncthreads();
    for (int off = 1; off < 1024; off <<= 1) {
        int t = (tid >= off) ? part[tid - off] : 0;
        __syncthreads();
        part[tid] += t;
        __syncthreads();
    }
    int run = part[tid] - sum;  // exclusive prefix of this segment
    for (int i = beg; i < end; ++i) {
        int v = counts[i];
        row_off[i] = run;
        cursor[i] = run;
        inv_deg[i] = 1.0f / fmaxf((float)v, 1.0f);
        run += v;
    }
    if (tid == 1023) row_off[N_NODES] = part[1023];
}

__global__ void fill_kernel(const int* __restrict__ ei, int* __restrict__ cursor,
                            int* __restrict__ csr_src) {
    int e = blockIdx.x * blockDim.x + threadIdx.x;
    if (e < N_EDGES) {
        int s = ei[e];
        int d = ei[N_EDGES + e];
        s = (s < 0) ? 0 : (s >= N_NODES ? N_NODES - 1 : s);
        d = (d < 0) ? 0 : (d >= N_NODES ? N_NODES - 1 : d);
        int pos = atomicAdd(&cursor[d], 1);
        if (pos >= 0 && pos < N_EDGES) csr_src[pos] = s;
    }
}

// ---------------- weight packs ----------------

// Wpk1[n][k] bf16, n in [0,256), k in [0,256): k<128 -> W1l[k][n], else W1r[k-128][n]
__global__ void pack_w1(const float* __restrict__ W1l, const float* __restrict__ W1r,
                        unsigned short* __restrict__ Wpk) {
    int n = blockIdx.x;
    int k = threadIdx.x;
    float v = (k < F_IN) ? W1l[(size_t)k * HIDDEN + n] : W1r[(size_t)(k - F_IN) * HIDDEN + n];
    Wpk[(size_t)n * 256 + k] = f2bf(v);
}

// Wpk2[n][k] bf16, n in [0,64) (cols 40..63 zero), k in [0,512): k<256 -> W2l[k][n], else W2r
__global__ void pack_w2(const float* __restrict__ W2l, const float* __restrict__ W2r,
                        unsigned short* __restrict__ Wpk2) {
    int n = blockIdx.x;   // 0..63
    int k = threadIdx.x;  // 0..511
    float v = 0.f;
    if (n < N_CLASSES)
        v = (k < HIDDEN) ? W2l[(size_t)k * N_CLASSES + n] : W2r[(size_t)(k - HIDDEN) * N_CLASSES + n];
    Wpk2[(size_t)n * 512 + k] = f2bf(v);
}

// ---------------- layer 1: gather-mean + MFMA GEMM + relu -> h (bf16) ----------------
// 256 threads (4 waves), 16 nodes/block. LDS A-tile [16][256] bf16 (stride 264).

#define AS1_STRIDE 264

__global__ __launch_bounds__(256) void gemm1_fused(
    const float* __restrict__ x, const int* __restrict__ row_off,
    const int* __restrict__ csr_src, const float* __restrict__ inv_deg,
    const unsigned short* __restrict__ Wpk, const float* __restrict__ b1,
    unsigned short* __restrict__ h16) {
    __shared__ __align__(16) unsigned short As[16][AS1_STRIDE];
    int n0 = blockIdx.x * 16;
    int tid = threadIdx.x;
    int wave = tid >> 6;
    int lane = tid & 63;

    for (int j = wave; j < 16; j += 4) {
        int n = n0 + j;
        int e0 = row_off[n], e1 = row_off[n + 1];
        float ax = 0.f, ay = 0.f;
        int e = e0;
        for (; e + 3 < e1; e += 4) {
            int s0 = csr_src[e], s1 = csr_src[e + 1];
            int s2 = csr_src[e + 2], s3 = csr_src[e + 3];
            float2 v0 = *reinterpret_cast<const float2*>(x + (size_t)s0 * F_IN + lane * 2);
            float2 v1 = *reinterpret_cast<const float2*>(x + (size_t)s1 * F_IN + lane * 2);
            float2 v2 = *reinterpret_cast<const float2*>(x + (size_t)s2 * F_IN + lane * 2);
            float2 v3 = *reinterpret_cast<const float2*>(x + (size_t)s3 * F_IN + lane * 2);
            ax += (v0.x + v1.x) + (v2.x + v3.x);
            ay += (v0.y + v1.y) + (v2.y + v3.y);
        }
        for (; e < e1; ++e) {
            int s0 = csr_src[e];
            float2 v0 = *reinterpret_cast<const float2*>(x + (size_t)s0 * F_IN + lane * 2);
            ax += v0.x;
            ay += v0.y;
        }
        float id = inv_deg[n];
        unsigned int pm = (unsigned int)f2bf(ax * id) | ((unsigned int)f2bf(ay * id) << 16);
        *reinterpret_cast<unsigned int*>(&As[j][lane * 2]) = pm;
        float2 xv = *reinterpret_cast<const float2*>(x + (size_t)n * F_IN + lane * 2);
        unsigned int px = (unsigned int)f2bf(xv.x) | ((unsigned int)f2bf(xv.y) << 16);
        *reinterpret_cast<unsigned int*>(&As[j][F_IN + lane * 2]) = px;
    }
    __syncthreads();

    int mrow = lane & 15;
    int kg = lane >> 4;
    f32x4 acc0 = {0.f, 0.f, 0.f, 0.f};
    f32x4 acc1 = {0.f, 0.f, 0.f, 0.f};
    f32x4 acc2 = {0.f, 0.f, 0.f, 0.f};
    f32x4 acc3 = {0.f, 0.f, 0.f, 0.f};
    const unsigned short* wp = Wpk + ((size_t)(wave * 4) * 16 + mrow) * 256 + kg * 8;
#pragma unroll
    for (int ks = 0; ks < 8; ++ks) {
        bf16x8 a = *reinterpret_cast<const bf16x8*>(&As[mrow][ks * 32 + kg * 8]);
        bf16x8 b0 = *reinterpret_cast<const bf16x8*>(wp + 0 * 16 * 256 + ks * 32);
        bf16x8 b1f = *reinterpret_cast<const bf16x8*>(wp + 1 * 16 * 256 + ks * 32);
        bf16x8 b2 = *reinterpret_cast<const bf16x8*>(wp + 2 * 16 * 256 + ks * 32);
        bf16x8 b3 = *reinterpret_cast<const bf16x8*>(wp + 3 * 16 * 256 + ks * 32);
        acc0 = __builtin_amdgcn_mfma_f32_16x16x32_bf16(a, b0, acc0, 0, 0, 0);
        acc1 = __builtin_amdgcn_mfma_f32_16x16x32_bf16(a, b1f, acc1, 0, 0, 0);
        acc2 = __builtin_amdgcn_mfma_f32_16x16x32_bf16(a, b2, acc2, 0, 0, 0);
        acc3 = __builtin_amdgcn_mfma_f32_16x16x32_bf16(a, b3, acc3, 0, 0, 0);
    }
    f32x4 accs[4] = {acc0, acc1, acc2, acc3};
#pragma unroll
    for (int i = 0; i < 4; ++i) {
        int n = (wave * 4 + i) * 16 + mrow;
        float bb = b1[n];
#pragma unroll
        for (int r = 0; r < 4; ++r) {
            int row = kg * 4 + r;
            h16[(size_t)(n0 + row) * HIDDEN + n] = f2bf(fmaxf(accs[i][r] + bb, 0.f));
        }
    }
}

// ---------------- layer 2: gather-mean + MFMA GEMM + log_softmax ----------------
// 512 threads (8 waves), 32 nodes/block. LDS A-tile [32][512] bf16 (stride 520).
// Wave w -> (mt, nt) = (w>>2, w&3); D tile = rows mt*16.., cols nt*16..

#define NB2 32
#define AS2_STRIDE 520

__global__ __launch_bounds__(512) void gemm2_fused(
    const unsigned short* __restrict__ h16, const int* __restrict__ row_off,
    const int* __restrict__ csr_src, const float* __restrict__ inv_deg,
    const unsigned short* __restrict__ Wpk2, const float* __restrict__ b2,
    float* __restrict__ out) {
    __shared__ __align__(16) unsigned short As[NB2][AS2_STRIDE];
    __shared__ float out_s[NB2][40];
    __shared__ float lse[NB2];
    int n0 = blockIdx.x * NB2;
    int tid = threadIdx.x;
    int wave = tid >> 6;
    int lane = tid & 63;

    // ---- gather phase: 4 nodes/wave, edge loop unrolled x4 ----
    for (int j = wave; j < NB2; j += 8) {
        int n = n0 + j;
        if (n < N_NODES) {
            int e0 = row_off[n], e1 = row_off[n + 1];
            float ax = 0.f, ay = 0.f, az = 0.f, aw = 0.f;
            int e = e0;
            for (; e + 3 < e1; e += 4) {
                int s0 = csr_src[e], s1 = csr_src[e + 1];
                int s2 = csr_src[e + 2], s3 = csr_src[e + 3];
                ushort4 v0 = *reinterpret_cast<const ushort4*>(h16 + (size_t)s0 * HIDDEN + lane * 4);
                ushort4 v1 = *reinterpret_cast<const ushort4*>(h16 + (size_t)s1 * HIDDEN + lane * 4);
                ushort4 v2 = *reinterpret_cast<const ushort4*>(h16 + (size_t)s2 * HIDDEN + lane * 4);
                ushort4 v3 = *reinterpret_cast<const ushort4*>(h16 + (size_t)s3 * HIDDEN + lane * 4);
                ax += (bf2f(v0.x) + bf2f(v1.x)) + (bf2f(v2.x) + bf2f(v3.x));
                ay += (bf2f(v0.y) + bf2f(v1.y)) + (bf2f(v2.y) + bf2f(v3.y));
                az += (bf2f(v0.z) + bf2f(v1.z)) + (bf2f(v2.z) + bf2f(v3.z));
                aw += (bf2f(v0.w) + bf2f(v1.w)) + (bf2f(v2.w) + bf2f(v3.w));
            }
            for (; e < e1; ++e) {
                int s0 = csr_src[e];
                ushort4 v0 = *reinterpret_cast<const ushort4*>(h16 + (size_t)s0 * HIDDEN + lane * 4);
                ax += bf2f(v0.x);
                ay += bf2f(v0.y);
                az += bf2f(v0.z);
                aw += bf2f(v0.w);
            }
            float id = inv_deg[n];
            ushort4 m;
            m.x = f2bf(ax * id); m.y = f2bf(ay * id); m.z = f2bf(az * id); m.w = f2bf(aw * id);
            *reinterpret_cast<ushort4*>(&As[j][lane * 4]) = m;
            *reinterpret_cast<ushort4*>(&As[j][HIDDEN + lane * 4]) =
                *reinterpret_cast<const ushort4*>(h16 + (size_t)n * HIDDEN + lane * 4);
        } else {
            ushort4 z = {0, 0, 0, 0};
            *reinterpret_cast<ushort4*>(&As[j][lane * 4]) = z;
            *reinterpret_cast<ushort4*>(&As[j][HIDDEN + lane * 4]) = z;
        }
    }
    __syncthreads();

    // ---- MFMA phase ----
    int mrow = lane & 15;
    int kg = lane >> 4;
    int mt = wave >> 2;  // 0..1
    int nt = wave & 3;   // 0..3
    f32x4 acc = {0.f, 0.f, 0.f, 0.f};
    const unsigned short* wp = Wpk2 + ((size_t)(nt * 16 + mrow)) * 512 + kg * 8;
#pragma unroll
    for (int ks = 0; ks < 16; ++ks) {
        bf16x8 a = *reinterpret_cast<const bf16x8*>(&As[mt * 16 + mrow][ks * 32 + kg * 8]);
        bf16x8 b = *reinterpret_cast<const bf16x8*>(wp + ks * 32);
        acc = __builtin_amdgcn_mfma_f32_16x16x32_bf16(a, b, acc, 0, 0, 0);
    }
    __syncthreads();  // done reading As; out_s is separate but keep phases ordered

    int col = nt * 16 + mrow;
    if (col < N_CLASSES) {
        float bb = b2[col];
#pragma unroll
        for (int r = 0; r < 4; ++r) {
            int row = mt * 16 + kg * 4 + r;
            out_s[row][col] = acc[r] + bb;
        }
    }
    __syncthreads();

    if (tid < NB2) {
        float m = -1e30f;
        for (int j = 0; j < N_CLASSES; ++j) m = fmaxf(m, out_s[tid][j]);
        float s = 0.f;
        for (int j = 0; j < N_CLASSES; ++j) s += expf(out_s[tid][j] - m);
        lse[tid] = m + logf(s);
    }
    __syncthreads();
    for (int idx = tid; idx < NB2 * N_CLASSES; idx += 512) {
        int i = idx / N_CLASSES;
        int n = n0 + i;
        if (n < N_NODES) out[(size_t)n * N_CLASSES + (idx % N_CLASSES)] = out_s[i][idx % N_CLASSES] - lse[i];
    }
}

// ---------------- launch ----------------

extern "C" void kernel_launch(void* const* d_in, const int* in_sizes, int n_in,
                              void* d_out, int out_size, void* d_ws, size_t ws_size,
                              hipStream_t stream) {
    const float* x = (const float*)d_in[0];
    const int* ei = (const int*)d_in[1];  // int32 per harness contract
    const float* W1l = (const float*)d_in[2];
    const float* W1r = (const float*)d_in[3];
    const float* b1 = (const float*)d_in[4];
    const float* W2l = (const float*)d_in[5];
    const float* W2r = (const float*)d_in[6];
    const float* b2 = (const float*)d_in[7];
    float* out = (float*)d_out;

    char* p = (char*)d_ws;
    size_t off = 0;
    auto take = [&](size_t bytes) -> void* {
        void* r = p + off;
        off = (off + bytes + 255) & ~(size_t)255;
        return r;
    };
    int* counts = (int*)take(N_NODES * sizeof(int));
    int* row_off = (int*)take((N_NODES + 1) * sizeof(int));
    int* cursor = (int*)take(N_NODES * sizeof(int));
    float* invdeg = (float*)take(N_NODES * sizeof(float));
    int* csr_src = (int*)take(N_EDGES * sizeof(int));
    unsigned short* h16 = (unsigned short*)take((size_t)N_NODES * HIDDEN * sizeof(unsigned short));
    unsigned short* Wpk1 = (unsigned short*)take(256 * 256 * sizeof(unsigned short));
    unsigned short* Wpk2 = (unsigned short*)take(64 * 512 * sizeof(unsigned short));
    // total ~= 30 MB

    zero_counts<<<(N_NODES + 255) / 256, 256, 0, stream>>>(counts);
    count_kernel<<<(N_EDGES + 255) / 256, 256, 0, stream>>>(ei + N_EDGES, counts);
    scan_kernel<<<1, 1024, 0, stream>>>(counts, row_off, cursor, invdeg);
    fill_kernel<<<(N_EDGES + 255) / 256, 256, 0, stream>>>(ei, cursor, csr_src);
    pack_w1<<<256, 256, 0, stream>>>(W1l, W1r, Wpk1);
    pack_w2<<<64, 512, 0, stream>>>(W2l, W2r, Wpk2);
    gemm1_fused<<<N_NODES / 16, 256, 0, stream>>>(x, row_off, csr_src, invdeg, Wpk1, b1, h16);
    gemm2_fused<<<(N_NODES + NB2 - 1) / NB2, 512, 0, stream>>>(h16, row_off, csr_src, invdeg,
                                                               Wpk2, b2, out);
}

// Round 6
// 311.087 us; speedup vs baseline: 2.1784x; 1.3952x over previous
//
#include <hip/hip_runtime.h>
#include <math.h>

#define N_NODES 50000
#define N_EDGES 800000
#define F_IN 128
#define HIDDEN 256
#define N_CLASSES 40

#define CHUNK 256
#define NCHUNK ((N_NODES + CHUNK - 1) / CHUNK)  // 196

typedef __attribute__((ext_vector_type(8))) short bf16x8;
typedef __attribute__((ext_vector_type(4))) float f32x4;

// ---------------- bf16 helpers ----------------

__device__ __forceinline__ float bf2f(unsigned short u) {
    unsigned int t = ((unsigned int)u) << 16;
    float f;
    __builtin_memcpy(&f, &t, 4);
    return f;
}

__device__ __forceinline__ unsigned short f2bf(float f) {
    unsigned int t;
    __builtin_memcpy(&t, &f, 4);
    unsigned int r = (t + 0x7fffu + ((t >> 16) & 1u)) >> 16;  // RNE
    return (unsigned short)r;
}

// ---------------- CSR build ----------------

__global__ void zero_counts(int* __restrict__ counts) {
    int i = blockIdx.x * blockDim.x + threadIdx.x;
    if (i < N_NODES) counts[i] = 0;
}

// edge_index arrives as int32 (JAX x64-disabled downgrades int64)
__global__ void count_kernel(const int* __restrict__ dst, int* __restrict__ counts) {
    int e = blockIdx.x * blockDim.x + threadIdx.x;
    if (e < N_EDGES) {
        int d = dst[e];
        d = (d < 0) ? 0 : (d >= N_NODES ? N_NODES - 1 : d);
        atomicAdd(&counts[d], 1);
    }
}

// --- hierarchical scan: partials -> scan partials -> apply ---

__global__ __launch_bounds__(256) void scan_partials(const int* __restrict__ counts,
                                                     int* __restrict__ bsum) {
    __shared__ int red[4];
    int b = blockIdx.x;
    int i = b * CHUNK + threadIdx.x;
    int v = (i < N_NODES) ? counts[i] : 0;
    // wave reduce (64 lanes)
    for (int off = 32; off > 0; off >>= 1) v += __shfl_down(v, off, 64);
    int wave = threadIdx.x >> 6;
    int lane = threadIdx.x & 63;
    if (lane == 0) red[wave] = v;
    __syncthreads();
    if (threadIdx.x == 0) bsum[b] = red[0] + red[1] + red[2] + red[3];
}

__global__ __launch_bounds__(256) void scan_bsums(int* __restrict__ bsum,
                                                  int* __restrict__ boff) {
    __shared__ int s[256];
    int tid = threadIdx.x;
    int v = (tid < NCHUNK) ? bsum[tid] : 0;
    s[tid] = v;
    __syncthreads();
    for (int off = 1; off < 256; off <<= 1) {
        int t = (tid >= off) ? s[tid - off] : 0;
        __syncthreads();
        s[tid] += t;
        __syncthreads();
    }
    if (tid < NCHUNK) boff[tid] = s[tid] - v;  // exclusive
    if (tid == NCHUNK - 1) boff[NCHUNK] = s[tid];  // total
}

__global__ __launch_bounds__(256) void scan_apply(const int* __restrict__ counts,
                                                  const int* __restrict__ boff,
                                                  int* __restrict__ row_off,
                                                  int* __restrict__ cursor,
                                                  float* __restrict__ inv_deg) {
    __shared__ int s[256];
    int b = blockIdx.x;
    int tid = threadIdx.x;
    int i = b * CHUNK + tid;
    int v = (i < N_NODES) ? counts[i] : 0;
    s[tid] = v;
    __syncthreads();
    for (int off = 1; off < 256; off <<= 1) {
        int t = (tid >= off) ? s[tid - off] : 0;
        __syncthreads();
        s[tid] += t;
        __syncthreads();
    }
    if (i < N_NODES) {
        int excl = boff[b] + s[tid] - v;
        row_off[i] = excl;
        cursor[i] = excl;
        inv_deg[i] = 1.0f / fmaxf((float)v, 1.0f);
        if (i == N_NODES - 1) row_off[N_NODES] = excl + v;
    }
}

__global__ void fill_kernel(const int* __restrict__ ei, int* __restrict__ cursor,
                            int* __restrict__ csr_src) {
    int e = blockIdx.x * blockDim.x + threadIdx.x;
    if (e < N_EDGES) {
        int s = ei[e];
        int d = ei[N_EDGES + e];
        s = (s < 0) ? 0 : (s >= N_NODES ? N_NODES - 1 : s);
        d = (d < 0) ? 0 : (d >= N_NODES ? N_NODES - 1 : d);
        int pos = atomicAdd(&cursor[d], 1);
        if (pos >= 0 && pos < N_EDGES) csr_src[pos] = s;
    }
}

// ---------------- weight packs ----------------

// Wpk1[n][k] bf16, n in [0,256), k in [0,256): k<128 -> W1l[k][n], else W1r[k-128][n]
__global__ void pack_w1(const float* __restrict__ W1l, const float* __restrict__ W1r,
                        unsigned short* __restrict__ Wpk) {
    int n = blockIdx.x;
    int k = threadIdx.x;
    float v = (k < F_IN) ? W1l[(size_t)k * HIDDEN + n] : W1r[(size_t)(k - F_IN) * HIDDEN + n];
    Wpk[(size_t)n * 256 + k] = f2bf(v);
}

// Wpk2[n][k] bf16, n in [0,64) (cols 40..63 zero), k in [0,512): k<256 -> W2l[k][n], else W2r
__global__ void pack_w2(const float* __restrict__ W2l, const float* __restrict__ W2r,
                        unsigned short* __restrict__ Wpk2) {
    int n = blockIdx.x;   // 0..63
    int k = threadIdx.x;  // 0..511
    float v = 0.f;
    if (n < N_CLASSES)
        v = (k < HIDDEN) ? W2l[(size_t)k * N_CLASSES + n] : W2r[(size_t)(k - HIDDEN) * N_CLASSES + n];
    Wpk2[(size_t)n * 512 + k] = f2bf(v);
}

// ---------------- layer 1: gather-mean + MFMA GEMM + relu -> h (bf16) ----------------
// 256 threads (4 waves), 16 nodes/block. LDS A-tile [16][256] bf16 (stride 264).

#define AS1_STRIDE 264

__global__ __launch_bounds__(256) void gemm1_fused(
    const float* __restrict__ x, const int* __restrict__ row_off,
    const int* __restrict__ csr_src, const float* __restrict__ inv_deg,
    const unsigned short* __restrict__ Wpk, const float* __restrict__ b1,
    unsigned short* __restrict__ h16) {
    __shared__ __align__(16) unsigned short As[16][AS1_STRIDE];
    int n0 = blockIdx.x * 16;
    int tid = threadIdx.x;
    int wave = tid >> 6;
    int lane = tid & 63;

    for (int j = wave; j < 16; j += 4) {
        int n = n0 + j;
        int e0 = row_off[n], e1 = row_off[n + 1];
        float ax = 0.f, ay = 0.f;
        int e = e0;
        for (; e + 3 < e1; e += 4) {
            int s0 = csr_src[e], s1 = csr_src[e + 1];
            int s2 = csr_src[e + 2], s3 = csr_src[e + 3];
            float2 v0 = *reinterpret_cast<const float2*>(x + (size_t)s0 * F_IN + lane * 2);
            float2 v1 = *reinterpret_cast<const float2*>(x + (size_t)s1 * F_IN + lane * 2);
            float2 v2 = *reinterpret_cast<const float2*>(x + (size_t)s2 * F_IN + lane * 2);
            float2 v3 = *reinterpret_cast<const float2*>(x + (size_t)s3 * F_IN + lane * 2);
            ax += (v0.x + v1.x) + (v2.x + v3.x);
            ay += (v0.y + v1.y) + (v2.y + v3.y);
        }
        for (; e < e1; ++e) {
            int s0 = csr_src[e];
            float2 v0 = *reinterpret_cast<const float2*>(x + (size_t)s0 * F_IN + lane * 2);
            ax += v0.x;
            ay += v0.y;
        }
        float id = inv_deg[n];
        unsigned int pm = (unsigned int)f2bf(ax * id) | ((unsigned int)f2bf(ay * id) << 16);
        *reinterpret_cast<unsigned int*>(&As[j][lane * 2]) = pm;
        float2 xv = *reinterpret_cast<const float2*>(x + (size_t)n * F_IN + lane * 2);
        unsigned int px = (unsigned int)f2bf(xv.x) | ((unsigned int)f2bf(xv.y) << 16);
        *reinterpret_cast<unsigned int*>(&As[j][F_IN + lane * 2]) = px;
    }
    __syncthreads();

    int mrow = lane & 15;
    int kg = lane >> 4;
    f32x4 acc0 = {0.f, 0.f, 0.f, 0.f};
    f32x4 acc1 = {0.f, 0.f, 0.f, 0.f};
    f32x4 acc2 = {0.f, 0.f, 0.f, 0.f};
    f32x4 acc3 = {0.f, 0.f, 0.f, 0.f};
    const unsigned short* wp = Wpk + ((size_t)(wave * 4) * 16 + mrow) * 256 + kg * 8;
#pragma unroll
    for (int ks = 0; ks < 8; ++ks) {
        bf16x8 a = *reinterpret_cast<const bf16x8*>(&As[mrow][ks * 32 + kg * 8]);
        bf16x8 b0 = *reinterpret_cast<const bf16x8*>(wp + 0 * 16 * 256 + ks * 32);
        bf16x8 b1f = *reinterpret_cast<const bf16x8*>(wp + 1 * 16 * 256 + ks * 32);
        bf16x8 b2 = *reinterpret_cast<const bf16x8*>(wp + 2 * 16 * 256 + ks * 32);
        bf16x8 b3 = *reinterpret_cast<const bf16x8*>(wp + 3 * 16 * 256 + ks * 32);
        acc0 = __builtin_amdgcn_mfma_f32_16x16x32_bf16(a, b0, acc0, 0, 0, 0);
        acc1 = __builtin_amdgcn_mfma_f32_16x16x32_bf16(a, b1f, acc1, 0, 0, 0);
        acc2 = __builtin_amdgcn_mfma_f32_16x16x32_bf16(a, b2, acc2, 0, 0, 0);
        acc3 = __builtin_amdgcn_mfma_f32_16x16x32_bf16(a, b3, acc3, 0, 0, 0);
    }
    f32x4 accs[4] = {acc0, acc1, acc2, acc3};
#pragma unroll
    for (int i = 0; i < 4; ++i) {
        int n = (wave * 4 + i) * 16 + mrow;
        float bb = b1[n];
#pragma unroll
        for (int r = 0; r < 4; ++r) {
            int row = kg * 4 + r;
            h16[(size_t)(n0 + row) * HIDDEN + n] = f2bf(fmaxf(accs[i][r] + bb, 0.f));
        }
    }
}

// ---------------- layer 2: gather-mean + MFMA GEMM + log_softmax ----------------
// 512 threads (8 waves), 32 nodes/block. LDS A-tile [32][512] bf16 (stride 520).
// Wave w -> (mt, nt) = (w>>2, w&3); D tile = rows mt*16.., cols nt*16..

#define NB2 32
#define AS2_STRIDE 520

__global__ __launch_bounds__(512) void gemm2_fused(
    const unsigned short* __restrict__ h16, const int* __restrict__ row_off,
    const int* __restrict__ csr_src, const float* __restrict__ inv_deg,
    const unsigned short* __restrict__ Wpk2, const float* __restrict__ b2,
    float* __restrict__ out) {
    __shared__ __align__(16) unsigned short As[NB2][AS2_STRIDE];
    __shared__ float out_s[NB2][40];
    __shared__ float lse[NB2];
    int n0 = blockIdx.x * NB2;
    int tid = threadIdx.x;
    int wave = tid >> 6;
    int lane = tid & 63;

    // ---- gather phase: 4 nodes/wave, edge loop unrolled x4 ----
    for (int j = wave; j < NB2; j += 8) {
        int n = n0 + j;
        if (n < N_NODES) {
            int e0 = row_off[n], e1 = row_off[n + 1];
            float ax = 0.f, ay = 0.f, az = 0.f, aw = 0.f;
            int e = e0;
            for (; e + 3 < e1; e += 4) {
                int s0 = csr_src[e], s1 = csr_src[e + 1];
                int s2 = csr_src[e + 2], s3 = csr_src[e + 3];
                ushort4 v0 = *reinterpret_cast<const ushort4*>(h16 + (size_t)s0 * HIDDEN + lane * 4);
                ushort4 v1 = *reinterpret_cast<const ushort4*>(h16 + (size_t)s1 * HIDDEN + lane * 4);
                ushort4 v2 = *reinterpret_cast<const ushort4*>(h16 + (size_t)s2 * HIDDEN + lane * 4);
                ushort4 v3 = *reinterpret_cast<const ushort4*>(h16 + (size_t)s3 * HIDDEN + lane * 4);
                ax += (bf2f(v0.x) + bf2f(v1.x)) + (bf2f(v2.x) + bf2f(v3.x));
                ay += (bf2f(v0.y) + bf2f(v1.y)) + (bf2f(v2.y) + bf2f(v3.y));
                az += (bf2f(v0.z) + bf2f(v1.z)) + (bf2f(v2.z) + bf2f(v3.z));
                aw += (bf2f(v0.w) + bf2f(v1.w)) + (bf2f(v2.w) + bf2f(v3.w));
            }
            for (; e < e1; ++e) {
                int s0 = csr_src[e];
                ushort4 v0 = *reinterpret_cast<const ushort4*>(h16 + (size_t)s0 * HIDDEN + lane * 4);
                ax += bf2f(v0.x);
                ay += bf2f(v0.y);
                az += bf2f(v0.z);
                aw += bf2f(v0.w);
            }
            float id = inv_deg[n];
            ushort4 m;
            m.x = f2bf(ax * id); m.y = f2bf(ay * id); m.z = f2bf(az * id); m.w = f2bf(aw * id);
            *reinterpret_cast<ushort4*>(&As[j][lane * 4]) = m;
            *reinterpret_cast<ushort4*>(&As[j][HIDDEN + lane * 4]) =
                *reinterpret_cast<const ushort4*>(h16 + (size_t)n * HIDDEN + lane * 4);
        } else {
            ushort4 z = {0, 0, 0, 0};
            *reinterpret_cast<ushort4*>(&As[j][lane * 4]) = z;
            *reinterpret_cast<ushort4*>(&As[j][HIDDEN + lane * 4]) = z;
        }
    }
    __syncthreads();

    // ---- MFMA phase ----
    int mrow = lane & 15;
    int kg = lane >> 4;
    int mt = wave >> 2;  // 0..1
    int nt = wave & 3;   // 0..3
    f32x4 acc = {0.f, 0.f, 0.f, 0.f};
    const unsigned short* wp = Wpk2 + ((size_t)(nt * 16 + mrow)) * 512 + kg * 8;
#pragma unroll
    for (int ks = 0; ks < 16; ++ks) {
        bf16x8 a = *reinterpret_cast<const bf16x8*>(&As[mt * 16 + mrow][ks * 32 + kg * 8]);
        bf16x8 b = *reinterpret_cast<const bf16x8*>(wp + ks * 32);
        acc = __builtin_amdgcn_mfma_f32_16x16x32_bf16(a, b, acc, 0, 0, 0);
    }
    __syncthreads();

    int col = nt * 16 + mrow;
    if (col < N_CLASSES) {
        float bb = b2[col];
#pragma unroll
        for (int r = 0; r < 4; ++r) {
            int row = mt * 16 + kg * 4 + r;
            out_s[row][col] = acc[r] + bb;
        }
    }
    __syncthreads();

    if (tid < NB2) {
        float m = -1e30f;
        for (int j = 0; j < N_CLASSES; ++j) m = fmaxf(m, out_s[tid][j]);
        float s = 0.f;
        for (int j = 0; j < N_CLASSES; ++j) s += expf(out_s[tid][j] - m);
        lse[tid] = m + logf(s);
    }
    __syncthreads();
    for (int idx = tid; idx < NB2 * N_CLASSES; idx += 512) {
        int i = idx / N_CLASSES;
        int n = n0 + i;
        if (n < N_NODES) out[(size_t)n * N_CLASSES + (idx % N_CLASSES)] = out_s[i][idx % N_CLASSES] - lse[i];
    }
}

// ---------------- launch ----------------

extern "C" void kernel_launch(void* const* d_in, const int* in_sizes, int n_in,
                              void* d_out, int out_size, void* d_ws, size_t ws_size,
                              hipStream_t stream) {
    const float* x = (const float*)d_in[0];
    const int* ei = (const int*)d_in[1];  // int32 per harness contract
    const float* W1l = (const float*)d_in[2];
    const float* W1r = (const float*)d_in[3];
    const float* b1 = (const float*)d_in[4];
    const float* W2l = (const float*)d_in[5];
    const float* W2r = (const float*)d_in[6];
    const float* b2 = (const float*)d_in[7];
    float* out = (float*)d_out;

    char* p = (char*)d_ws;
    size_t off = 0;
    auto take = [&](size_t bytes) -> void* {
        void* r = p + off;
        off = (off + bytes + 255) & ~(size_t)255;
        return r;
    };
    int* counts = (int*)take(N_NODES * sizeof(int));
    int* row_off = (int*)take((N_NODES + 1) * sizeof(int));
    int* cursor = (int*)take(N_NODES * sizeof(int));
    float* invdeg = (float*)take(N_NODES * sizeof(float));
    int* csr_src = (int*)take(N_EDGES * sizeof(int));
    int* bsum = (int*)take((NCHUNK + 1) * sizeof(int));
    int* boff = (int*)take((NCHUNK + 1) * sizeof(int));
    unsigned short* h16 = (unsigned short*)take((size_t)N_NODES * HIDDEN * sizeof(unsigned short));
    unsigned short* Wpk1 = (unsigned short*)take(256 * 256 * sizeof(unsigned short));
    unsigned short* Wpk2 = (unsigned short*)take(64 * 512 * sizeof(unsigned short));
    // total ~= 30 MB

    zero_counts<<<(N_NODES + 255) / 256, 256, 0, stream>>>(counts);
    count_kernel<<<(N_EDGES + 255) / 256, 256, 0, stream>>>(ei + N_EDGES, counts);
    scan_partials<<<NCHUNK, 256, 0, stream>>>(counts, bsum);
    scan_bsums<<<1, 256, 0, stream>>>(bsum, boff);
    scan_apply<<<NCHUNK, 256, 0, stream>>>(counts, boff, row_off, cursor, invdeg);
    fill_kernel<<<(N_EDGES + 255) / 256, 256, 0, stream>>>(ei, cursor, csr_src);
    pack_w1<<<256, 256, 0, stream>>>(W1l, W1r, Wpk1);
    pack_w2<<<64, 512, 0, stream>>>(W2l, W2r, Wpk2);
    gemm1_fused<<<N_NODES / 16, 256, 0, stream>>>(x, row_off, csr_src, invdeg, Wpk1, b1, h16);
    gemm2_fused<<<(N_NODES + NB2 - 1) / NB2, 512, 0, stream>>>(h16, row_off, csr_src, invdeg,
                                                               Wpk2, b2, out);
}

// Round 7
// 291.627 us; speedup vs baseline: 2.3238x; 1.0667x over previous
//
#include <hip/hip_runtime.h>
#include <math.h>

#define N_NODES 50000
#define N_EDGES 800000
#define F_IN 128
#define HIDDEN 256
#define N_CLASSES 40

#define CHUNK 256
#define NCHUNK ((N_NODES + CHUNK - 1) / CHUNK)  // 196

typedef __attribute__((ext_vector_type(8))) short bf16x8;
typedef __attribute__((ext_vector_type(4))) float f32x4;
typedef __attribute__((ext_vector_type(8))) unsigned short u16x8;

// ---------------- bf16 helpers ----------------

__device__ __forceinline__ float bf2f(unsigned short u) {
    unsigned int t = ((unsigned int)u) << 16;
    float f;
    __builtin_memcpy(&f, &t, 4);
    return f;
}

__device__ __forceinline__ unsigned short f2bf(float f) {
    unsigned int t;
    __builtin_memcpy(&t, &f, 4);
    unsigned int r = (t + 0x7fffu + ((t >> 16) & 1u)) >> 16;  // RNE
    return (unsigned short)r;
}

// ---------------- CSR build ----------------

__global__ void zero_counts(int* __restrict__ counts) {
    int i = blockIdx.x * blockDim.x + threadIdx.x;
    if (i < N_NODES) counts[i] = 0;
}

// edge_index arrives as int32 (JAX x64-disabled downgrades int64)
__global__ void count_kernel(const int* __restrict__ dst, int* __restrict__ counts) {
    int e = blockIdx.x * blockDim.x + threadIdx.x;
    if (e < N_EDGES) {
        int d = dst[e];
        d = (d < 0) ? 0 : (d >= N_NODES ? N_NODES - 1 : d);
        atomicAdd(&counts[d], 1);
    }
}

__global__ __launch_bounds__(256) void scan_partials(const int* __restrict__ counts,
                                                     int* __restrict__ bsum) {
    __shared__ int red[4];
    int b = blockIdx.x;
    int i = b * CHUNK + threadIdx.x;
    int v = (i < N_NODES) ? counts[i] : 0;
    for (int off = 32; off > 0; off >>= 1) v += __shfl_down(v, off, 64);
    int wave = threadIdx.x >> 6;
    int lane = threadIdx.x & 63;
    if (lane == 0) red[wave] = v;
    __syncthreads();
    if (threadIdx.x == 0) bsum[b] = red[0] + red[1] + red[2] + red[3];
}

__global__ __launch_bounds__(256) void scan_bsums(int* __restrict__ bsum,
                                                  int* __restrict__ boff) {
    __shared__ int s[256];
    int tid = threadIdx.x;
    int v = (tid < NCHUNK) ? bsum[tid] : 0;
    s[tid] = v;
    __syncthreads();
    for (int off = 1; off < 256; off <<= 1) {
        int t = (tid >= off) ? s[tid - off] : 0;
        __syncthreads();
        s[tid] += t;
        __syncthreads();
    }
    if (tid < NCHUNK) boff[tid] = s[tid] - v;
    if (tid == NCHUNK - 1) boff[NCHUNK] = s[tid];
}

__global__ __launch_bounds__(256) void scan_apply(const int* __restrict__ counts,
                                                  const int* __restrict__ boff,
                                                  int* __restrict__ row_off,
                                                  int* __restrict__ cursor,
                                                  float* __restrict__ inv_deg) {
    __shared__ int s[256];
    int b = blockIdx.x;
    int tid = threadIdx.x;
    int i = b * CHUNK + tid;
    int v = (i < N_NODES) ? counts[i] : 0;
    s[tid] = v;
    __syncthreads();
    for (int off = 1; off < 256; off <<= 1) {
        int t = (tid >= off) ? s[tid - off] : 0;
        __syncthreads();
        s[tid] += t;
        __syncthreads();
    }
    if (i < N_NODES) {
        int excl = boff[b] + s[tid] - v;
        row_off[i] = excl;
        cursor[i] = excl;
        inv_deg[i] = 1.0f / fmaxf((float)v, 1.0f);
        if (i == N_NODES - 1) row_off[N_NODES] = excl + v;
    }
}

__global__ void fill_kernel(const int* __restrict__ ei, int* __restrict__ cursor,
                            int* __restrict__ csr_src) {
    int e = blockIdx.x * blockDim.x + threadIdx.x;
    if (e < N_EDGES) {
        int s = ei[e];
        int d = ei[N_EDGES + e];
        s = (s < 0) ? 0 : (s >= N_NODES ? N_NODES - 1 : s);
        d = (d < 0) ? 0 : (d >= N_NODES ? N_NODES - 1 : d);
        int pos = atomicAdd(&cursor[d], 1);
        if (pos >= 0 && pos < N_EDGES) csr_src[pos] = s;
    }
}

// ---------------- x -> bf16 conversion ----------------

__global__ void conv_x16(const float* __restrict__ x, unsigned short* __restrict__ x16) {
    int i = blockIdx.x * blockDim.x + threadIdx.x;  // 4 elems/thread
    if (i < N_NODES * F_IN / 4) {
        float4 v = reinterpret_cast<const float4*>(x)[i];
        ushort4 o;
        o.x = f2bf(v.x); o.y = f2bf(v.y); o.z = f2bf(v.z); o.w = f2bf(v.w);
        reinterpret_cast<ushort4*>(x16)[i] = o;
    }
}

// ---------------- weight packs ----------------

__global__ void pack_w1(const float* __restrict__ W1l, const float* __restrict__ W1r,
                        unsigned short* __restrict__ Wpk) {
    int n = blockIdx.x;
    int k = threadIdx.x;
    float v = (k < F_IN) ? W1l[(size_t)k * HIDDEN + n] : W1r[(size_t)(k - F_IN) * HIDDEN + n];
    Wpk[(size_t)n * 256 + k] = f2bf(v);
}

__global__ void pack_w2(const float* __restrict__ W2l, const float* __restrict__ W2r,
                        unsigned short* __restrict__ Wpk2) {
    int n = blockIdx.x;   // 0..63
    int k = threadIdx.x;  // 0..511
    float v = 0.f;
    if (n < N_CLASSES)
        v = (k < HIDDEN) ? W2l[(size_t)k * N_CLASSES + n] : W2r[(size_t)(k - HIDDEN) * N_CLASSES + n];
    Wpk2[(size_t)n * 512 + k] = f2bf(v);
}

// ---------------- layer 1: split-wave gather + MFMA + relu -> h16 ----------------
// 256 threads (4 waves), 16 nodes/block. Half-wave per edge; lane covers 4 features.

#define AS1_STRIDE 264

template <bool XBF16>
__global__ __launch_bounds__(256) void gemm1_fused_t(
    const float* __restrict__ x, const unsigned short* __restrict__ x16,
    const int* __restrict__ row_off, const int* __restrict__ csr_src,
    const float* __restrict__ inv_deg, const unsigned short* __restrict__ Wpk,
    const float* __restrict__ b1, unsigned short* __restrict__ h16) {
    __shared__ __align__(16) unsigned short As[16][AS1_STRIDE];
    int n0 = blockIdx.x * 16;
    int tid = threadIdx.x;
    int wave = tid >> 6;
    int lane = tid & 63;
    int half = lane >> 5;
    int fl = lane & 31;

    for (int j = wave; j < 16; j += 4) {
        int n = n0 + j;
        int e0 = row_off[n], e1 = row_off[n + 1];
        int deg = e1 - e0;
        int npair = deg >> 1;
        float a0 = 0.f, a1 = 0.f, a2 = 0.f, a3 = 0.f;

        auto loadrow = [&](int s, float& r0, float& r1, float& r2, float& r3) {
            if constexpr (XBF16) {
                ushort4 v = *reinterpret_cast<const ushort4*>(x16 + (size_t)s * F_IN + fl * 4);
                r0 = bf2f(v.x); r1 = bf2f(v.y); r2 = bf2f(v.z); r3 = bf2f(v.w);
            } else {
                float4 v = *reinterpret_cast<const float4*>(x + (size_t)s * F_IN + fl * 4);
                r0 = v.x; r1 = v.y; r2 = v.z; r3 = v.w;
            }
        };

        int p = 0;
        for (; p + 3 < npair; p += 4) {  // 4 pairs = 8 edges, 4 loads in flight/lane
            int sA = csr_src[e0 + 2 * p + half];
            int sB = csr_src[e0 + 2 * p + 2 + half];
            int sC = csr_src[e0 + 2 * p + 4 + half];
            int sD = csr_src[e0 + 2 * p + 6 + half];
            float t0, t1, t2, t3, u0, u1, u2, u3, w0, w1, w2, w3, z0, z1, z2, z3;
            loadrow(sA, t0, t1, t2, t3);
            loadrow(sB, u0, u1, u2, u3);
            loadrow(sC, w0, w1, w2, w3);
            loadrow(sD, z0, z1, z2, z3);
            a0 += (t0 + u0) + (w0 + z0);
            a1 += (t1 + u1) + (w1 + z1);
            a2 += (t2 + u2) + (w2 + z2);
            a3 += (t3 + u3) + (w3 + z3);
        }
        for (; p < npair; ++p) {
            int s = csr_src[e0 + 2 * p + half];
            float t0, t1, t2, t3;
            loadrow(s, t0, t1, t2, t3);
            a0 += t0; a1 += t1; a2 += t2; a3 += t3;
        }
        if (deg & 1) {
            if (half == 0) {
                int s = csr_src[e1 - 1];
                float t0, t1, t2, t3;
                loadrow(s, t0, t1, t2, t3);
                a0 += t0; a1 += t1; a2 += t2; a3 += t3;
            }
        }
        a0 += __shfl_xor(a0, 32);
        a1 += __shfl_xor(a1, 32);
        a2 += __shfl_xor(a2, 32);
        a3 += __shfl_xor(a3, 32);
        if (half == 0) {
            float id = inv_deg[n];
            ushort4 m;
            m.x = f2bf(a0 * id); m.y = f2bf(a1 * id); m.z = f2bf(a2 * id); m.w = f2bf(a3 * id);
            *reinterpret_cast<ushort4*>(&As[j][fl * 4]) = m;
            float s0, s1, s2, s3;
            loadrow(n, s0, s1, s2, s3);
            ushort4 sv;
            sv.x = f2bf(s0); sv.y = f2bf(s1); sv.z = f2bf(s2); sv.w = f2bf(s3);
            *reinterpret_cast<ushort4*>(&As[j][F_IN + fl * 4]) = sv;
        }
    }
    __syncthreads();

    // ---- MFMA phase (unchanged, m89-verified layout) ----
    int mrow = lane & 15;
    int kg = lane >> 4;
    f32x4 acc0 = {0.f, 0.f, 0.f, 0.f};
    f32x4 acc1 = {0.f, 0.f, 0.f, 0.f};
    f32x4 acc2 = {0.f, 0.f, 0.f, 0.f};
    f32x4 acc3 = {0.f, 0.f, 0.f, 0.f};
    const unsigned short* wp = Wpk + ((size_t)(wave * 4) * 16 + mrow) * 256 + kg * 8;
#pragma unroll
    for (int ks = 0; ks < 8; ++ks) {
        bf16x8 a = *reinterpret_cast<const bf16x8*>(&As[mrow][ks * 32 + kg * 8]);
        bf16x8 b0 = *reinterpret_cast<const bf16x8*>(wp + 0 * 16 * 256 + ks * 32);
        bf16x8 b1f = *reinterpret_cast<const bf16x8*>(wp + 1 * 16 * 256 + ks * 32);
        bf16x8 b2 = *reinterpret_cast<const bf16x8*>(wp + 2 * 16 * 256 + ks * 32);
        bf16x8 b3 = *reinterpret_cast<const bf16x8*>(wp + 3 * 16 * 256 + ks * 32);
        acc0 = __builtin_amdgcn_mfma_f32_16x16x32_bf16(a, b0, acc0, 0, 0, 0);
        acc1 = __builtin_amdgcn_mfma_f32_16x16x32_bf16(a, b1f, acc1, 0, 0, 0);
        acc2 = __builtin_amdgcn_mfma_f32_16x16x32_bf16(a, b2, acc2, 0, 0, 0);
        acc3 = __builtin_amdgcn_mfma_f32_16x16x32_bf16(a, b3, acc3, 0, 0, 0);
    }
    f32x4 accs[4] = {acc0, acc1, acc2, acc3};
#pragma unroll
    for (int i = 0; i < 4; ++i) {
        int n = (wave * 4 + i) * 16 + mrow;
        float bb = b1[n];
#pragma unroll
        for (int r = 0; r < 4; ++r) {
            int row = kg * 4 + r;
            h16[(size_t)(n0 + row) * HIDDEN + n] = f2bf(fmaxf(accs[i][r] + bb, 0.f));
        }
    }
}

// ---------------- layer 2: split-wave gather + MFMA + log_softmax ----------------
// 512 threads (8 waves), 32 nodes/block. Half-wave per edge; lane covers 8 features (16B).

#define NB2 32
#define AS2_STRIDE 520

__global__ __launch_bounds__(512) void gemm2_fused(
    const unsigned short* __restrict__ h16, const int* __restrict__ row_off,
    const int* __restrict__ csr_src, const float* __restrict__ inv_deg,
    const unsigned short* __restrict__ Wpk2, const float* __restrict__ b2,
    float* __restrict__ out) {
    __shared__ __align__(16) unsigned short As[NB2][AS2_STRIDE];
    __shared__ float out_s[NB2][40];
    __shared__ float lse[NB2];
    int n0 = blockIdx.x * NB2;
    int tid = threadIdx.x;
    int wave = tid >> 6;
    int lane = tid & 63;
    int half = lane >> 5;
    int fl = lane & 31;

    for (int j = wave; j < NB2; j += 8) {
        int n = n0 + j;
        if (n < N_NODES) {
            int e0 = row_off[n], e1 = row_off[n + 1];
            int deg = e1 - e0;
            int npair = deg >> 1;
            float a[8] = {0.f, 0.f, 0.f, 0.f, 0.f, 0.f, 0.f, 0.f};
            int p = 0;
            for (; p + 3 < npair; p += 4) {  // 4 pairs = 8 edges, 4x16B loads in flight/lane
                int sA = csr_src[e0 + 2 * p + half];
                int sB = csr_src[e0 + 2 * p + 2 + half];
                int sC = csr_src[e0 + 2 * p + 4 + half];
                int sD = csr_src[e0 + 2 * p + 6 + half];
                u16x8 vA = *reinterpret_cast<const u16x8*>(h16 + (size_t)sA * HIDDEN + fl * 8);
                u16x8 vB = *reinterpret_cast<const u16x8*>(h16 + (size_t)sB * HIDDEN + fl * 8);
                u16x8 vC = *reinterpret_cast<const u16x8*>(h16 + (size_t)sC * HIDDEN + fl * 8);
                u16x8 vD = *reinterpret_cast<const u16x8*>(h16 + (size_t)sD * HIDDEN + fl * 8);
#pragma unroll
                for (int q = 0; q < 8; ++q)
                    a[q] += (bf2f(vA[q]) + bf2f(vB[q])) + (bf2f(vC[q]) + bf2f(vD[q]));
            }
            for (; p < npair; ++p) {
                int s = csr_src[e0 + 2 * p + half];
                u16x8 v = *reinterpret_cast<const u16x8*>(h16 + (size_t)s * HIDDEN + fl * 8);
#pragma unroll
                for (int q = 0; q < 8; ++q) a[q] += bf2f(v[q]);
            }
            if (deg & 1) {
                if (half == 0) {
                    int s = csr_src[e1 - 1];
                    u16x8 v = *reinterpret_cast<const u16x8*>(h16 + (size_t)s * HIDDEN + fl * 8);
#pragma unroll
                    for (int q = 0; q < 8; ++q) a[q] += bf2f(v[q]);
                }
            }
#pragma unroll
            for (int q = 0; q < 8; ++q) a[q] += __shfl_xor(a[q], 32);
            if (half == 0) {
                float id = inv_deg[n];
                u16x8 m;
#pragma unroll
                for (int q = 0; q < 8; ++q) m[q] = f2bf(a[q] * id);
                *reinterpret_cast<u16x8*>(&As[j][fl * 8]) = m;
                *reinterpret_cast<u16x8*>(&As[j][HIDDEN + fl * 8]) =
                    *reinterpret_cast<const u16x8*>(h16 + (size_t)n * HIDDEN + fl * 8);
            }
        } else {
            if (half == 0) {
                u16x8 z = {0, 0, 0, 0, 0, 0, 0, 0};
                *reinterpret_cast<u16x8*>(&As[j][fl * 8]) = z;
                *reinterpret_cast<u16x8*>(&As[j][HIDDEN + fl * 8]) = z;
            }
        }
    }
    __syncthreads();

    // ---- MFMA phase ----
    int mrow = lane & 15;
    int kg = lane >> 4;
    int mt = wave >> 2;  // 0..1
    int nt = wave & 3;   // 0..3
    f32x4 acc = {0.f, 0.f, 0.f, 0.f};
    const unsigned short* wp = Wpk2 + ((size_t)(nt * 16 + mrow)) * 512 + kg * 8;
#pragma unroll
    for (int ks = 0; ks < 16; ++ks) {
        bf16x8 a = *reinterpret_cast<const bf16x8*>(&As[mt * 16 + mrow][ks * 32 + kg * 8]);
        bf16x8 b = *reinterpret_cast<const bf16x8*>(wp + ks * 32);
        acc = __builtin_amdgcn_mfma_f32_16x16x32_bf16(a, b, acc, 0, 0, 0);
    }
    __syncthreads();

    int col = nt * 16 + mrow;
    if (col < N_CLASSES) {
        float bb = b2[col];
#pragma unroll
        for (int r = 0; r < 4; ++r) {
            int row = mt * 16 + kg * 4 + r;
            out_s[row][col] = acc[r] + bb;
        }
    }
    __syncthreads();

    if (tid < NB2) {
        float m = -1e30f;
        for (int j = 0; j < N_CLASSES; ++j) m = fmaxf(m, out_s[tid][j]);
        float s = 0.f;
        for (int j = 0; j < N_CLASSES; ++j) s += expf(out_s[tid][j] - m);
        lse[tid] = m + logf(s);
    }
    __syncthreads();
    for (int idx = tid; idx < NB2 * N_CLASSES; idx += 512) {
        int i = idx / N_CLASSES;
        int n = n0 + i;
        if (n < N_NODES) out[(size_t)n * N_CLASSES + (idx % N_CLASSES)] = out_s[i][idx % N_CLASSES] - lse[i];
    }
}

// ---------------- launch ----------------

extern "C" void kernel_launch(void* const* d_in, const int* in_sizes, int n_in,
                              void* d_out, int out_size, void* d_ws, size_t ws_size,
                              hipStream_t stream) {
    const float* x = (const float*)d_in[0];
    const int* ei = (const int*)d_in[1];  // int32 per harness contract
    const float* W1l = (const float*)d_in[2];
    const float* W1r = (const float*)d_in[3];
    const float* b1 = (const float*)d_in[4];
    const float* W2l = (const float*)d_in[5];
    const float* W2r = (const float*)d_in[6];
    const float* b2 = (const float*)d_in[7];
    float* out = (float*)d_out;

    char* p = (char*)d_ws;
    size_t off = 0;
    auto take = [&](size_t bytes) -> void* {
        void* r = p + off;
        off = (off + bytes + 255) & ~(size_t)255;
        return r;
    };
    int* counts = (int*)take(N_NODES * sizeof(int));
    int* row_off = (int*)take((N_NODES + 1) * sizeof(int));
    int* cursor = (int*)take(N_NODES * sizeof(int));
    float* invdeg = (float*)take(N_NODES * sizeof(float));
    int* csr_src = (int*)take(N_EDGES * sizeof(int));
    int* bsum = (int*)take((NCHUNK + 1) * sizeof(int));
    int* boff = (int*)take((NCHUNK + 1) * sizeof(int));
    unsigned short* h16 = (unsigned short*)take((size_t)N_NODES * HIDDEN * sizeof(unsigned short));
    unsigned short* Wpk1 = (unsigned short*)take(256 * 256 * sizeof(unsigned short));
    unsigned short* Wpk2 = (unsigned short*)take(64 * 512 * sizeof(unsigned short));
    // ~30 MB so far; x16 (12.8 MB) only if it fits
    size_t x16_bytes = (size_t)N_NODES * F_IN * sizeof(unsigned short);
    unsigned short* x16 = nullptr;
    if (off + x16_bytes <= ws_size) x16 = (unsigned short*)take(x16_bytes);

    zero_counts<<<(N_NODES + 255) / 256, 256, 0, stream>>>(counts);
    count_kernel<<<(N_EDGES + 255) / 256, 256, 0, stream>>>(ei + N_EDGES, counts);
    scan_partials<<<NCHUNK, 256, 0, stream>>>(counts, bsum);
    scan_bsums<<<1, 256, 0, stream>>>(bsum, boff);
    scan_apply<<<NCHUNK, 256, 0, stream>>>(counts, boff, row_off, cursor, invdeg);
    fill_kernel<<<(N_EDGES + 255) / 256, 256, 0, stream>>>(ei, cursor, csr_src);
    pack_w1<<<256, 256, 0, stream>>>(W1l, W1r, Wpk1);
    pack_w2<<<64, 512, 0, stream>>>(W2l, W2r, Wpk2);
    if (x16) {
        conv_x16<<<(N_NODES * F_IN / 4 + 255) / 256, 256, 0, stream>>>(x, x16);
        gemm1_fused_t<true><<<N_NODES / 16, 256, 0, stream>>>(x, x16, row_off, csr_src, invdeg,
                                                              Wpk1, b1, h16);
    } else {
        gemm1_fused_t<false><<<N_NODES / 16, 256, 0, stream>>>(x, x16, row_off, csr_src, invdeg,
                                                               Wpk1, b1, h16);
    }
    gemm2_fused<<<(N_NODES + NB2 - 1) / NB2, 512, 0, stream>>>(h16, row_off, csr_src, invdeg,
                                                               Wpk2, b2, out);
}